// Round 3
// baseline (587.839 us; speedup 1.0000x reference)
//
#include <hip/hip_runtime.h>
#include <math.h>

// Problem constants (match reference)
#define NB   64     // num_groups (B)
#define NG   32     // group_size (G)
#define ND   2000   // output dim D
#define NM   16     // m_samples
#define NE   16     // noise dim
#define NDIN 256
#define NK   272    // DIN + E
#define NWAVES 16   // waves per 1024-thread block

// IPF storage split (round-2 profile evidence):
//   VGPR=64 + WRITE_SIZE +16MB proved the allocator spills any ~64-float/thr
//   register-resident y0 (occupancy heuristic targets 8 waves/EU).  The spill
//   reload stream (512 B/thr/iter from L2) is per-CU L1<->L2 port bound
//   (~75 B/cyc -> 199us).  Fix: y0 columns live in LDS (separate 128 B/cyc
//   pipe); what doesn't fit streams from L2 and overlaps the LDS pipe.
#define LDST 608                       // threads t<608: both d-cols in LDS
#define YB   4096                      // byte offset of y region (after wred)
#define SMEM_BYTES (YB + 1216 * 128)   // 4 KB wred + 1216 cols * 128 B = 159744

__device__ __forceinline__ float clampf(float v, float lo, float hi) {
    return fminf(fmaxf(v, lo), hi);
}

__device__ __forceinline__ float softplusf(float v) {
    return (v > 20.f) ? v : log1pf(expf(v));
}

// Broadcast lane's value as a WAVE-UNIFORM (SGPR) value.
__device__ __forceinline__ float readlane_f(float v, int lane) {
    return __int_as_float(__builtin_amdgcn_readlane(__float_as_int(v), lane));
}

// Fully-packed butterfly: reduce v[0..31] (per-g partials) across 64 lanes in
// 32 shuffles.  Returns the wave total for g = (lane>>1)&31 (dup on pairs).
__device__ __forceinline__ float wave_sum32(float v[NG], int lane) {
    {   const bool hi = (lane & 32) != 0;
        #pragma unroll
        for (int k = 0; k < 16; ++k) {
            float s = hi ? v[k] : v[k + 16];
            float r = __shfl_xor(s, 32);
            v[k] = (hi ? v[k + 16] : v[k]) + r;
        }
    }
    {   const bool hi = (lane & 16) != 0;
        #pragma unroll
        for (int k = 0; k < 8; ++k) {
            float s = hi ? v[k] : v[k + 8];
            float r = __shfl_xor(s, 16);
            v[k] = (hi ? v[k + 8] : v[k]) + r;
        }
    }
    {   const bool hi = (lane & 8) != 0;
        #pragma unroll
        for (int k = 0; k < 4; ++k) {
            float s = hi ? v[k] : v[k + 4];
            float r = __shfl_xor(s, 8);
            v[k] = (hi ? v[k + 4] : v[k]) + r;
        }
    }
    {   const bool hi = (lane & 4) != 0;
        #pragma unroll
        for (int k = 0; k < 2; ++k) {
            float s = hi ? v[k] : v[k + 2];
            float r = __shfl_xor(s, 4);
            v[k] = (hi ? v[k + 2] : v[k]) + r;
        }
    }
    {   const bool hi = (lane & 2) != 0;
        float s = hi ? v[0] : v[1];
        float r = __shfl_xor(s, 2);
        v[0] = (hi ? v[1] : v[0]) + r;
    }
    v[0] += __shfl_xor(v[0], 1);
    return v[0];
}

// ---------------------------------------------------------------------------
// IPF path: thread owns d0=2t, d1=2t+1 (same pairing/FP order as the passing
// round-2 kernel => bit-identical numerics).  Columns are stored in LDS
// (t<608) or re-streamed from L2 (t>=608) each pass.  Column layout: 128 B
// contiguous, 16B-chunks rotated by ((k + t) & 7) so each ds_read_b128
// spreads its 64 lanes across all 32 banks (BW-floor optimal).
// Two passes/iter (col-dot, A-update, row-accumulate): live set ~50 VGPR,
// fits ANY budget the allocator picks -> no spill possible by design.
// ---------------------------------------------------------------------------
__device__ __forceinline__ void ipf_path(
        const float* __restrict__ xpT, const int* __restrict__ tsum,
        float* __restrict__ out, char* smem, int b, int t) {
    const int lane = t & 63, w = t >> 6;      // wave 0..15
    const int d0 = t * 2;
    const bool valid = (d0 < ND);             // t < 1000
    const bool lcls  = (t < LDST);            // LDS-resident columns
    const int g_own = (lane >> 1) & 31;
    const int rot = t & 7;

    float* wred = (float*)smem;               // [2][16][32] floats, dbuf
    char* base0 = smem + YB + (size_t)d0 * 128;
    char* base1 = base0 + 128;
    const float4* gp = (const float4*)(xpT + ((size_t)b * ND + d0) * NG);

    float Cc[2] = {0.f, 0.f};
    if (valid) {
        const int2 ci = *(const int2*)(tsum + (size_t)b * ND + d0);
        Cc[0] = (float)ci.x; Cc[1] = (float)ci.y;
    }
    float Ac[2] = {1.f, 1.f};
    float Bown = 1.f;                         // lane-pair's B[g_own]
    float Rown;                               // lane-pair's R[g_own]

    // prologue: load columns (softplus output >= 0, relu is identity),
    // stash LDS-class columns, compute row anchors R.
    {
        float v[NG];
        if (valid) {
            #pragma unroll
            for (int k = 0; k < 8; ++k) {
                const float4 a = gp[k];
                const float4 c = gp[8 + k];
                v[4*k+0] = a.x + c.x;
                v[4*k+1] = a.y + c.y;
                v[4*k+2] = a.z + c.z;
                v[4*k+3] = a.w + c.w;
                if (lcls) {
                    const int ro = 16 * ((k + rot) & 7);
                    *(float4*)(base0 + ro) = a;
                    *(float4*)(base1 + ro) = c;
                }
            }
        } else {
            #pragma unroll
            for (int g = 0; g < NG; ++g) v[g] = 0.f;
        }
        const float tot = wave_sum32(v, lane);
        if ((lane & 1) == 0) wred[w * NG + g_own] = tot;
        __syncthreads();
        float s = 0.f;
        #pragma unroll
        for (int w2 = 0; w2 < NWAVES; ++w2) s += wred[w2 * NG + g_own];
        Rown = s;
    }

    // 60 IPF iterations, ONE barrier each (double-buffered wred)
    for (int q = 1; q <= 60; ++q) {
        // ---- column pass: s(d) = sum_g y0[g,d] * B[g] ----
        float s0 = 0.f, s1 = 0.f;
        if (lcls) {
            #pragma unroll
            for (int k = 0; k < 8; ++k) {
                const int ro = 16 * ((k + rot) & 7);
                const float4 a = *(const float4*)(base0 + ro);
                const float4 c = *(const float4*)(base1 + ro);
                float bg;
                bg = readlane_f(Bown, 8*k+0); s0 += a.x * bg; s1 += c.x * bg;
                bg = readlane_f(Bown, 8*k+2); s0 += a.y * bg; s1 += c.y * bg;
                bg = readlane_f(Bown, 8*k+4); s0 += a.z * bg; s1 += c.z * bg;
                bg = readlane_f(Bown, 8*k+6); s0 += a.w * bg; s1 += c.w * bg;
            }
        } else if (valid) {
            #pragma unroll
            for (int k = 0; k < 8; ++k) {
                const float4 a = gp[k];
                const float4 c = gp[8 + k];
                float bg;
                bg = readlane_f(Bown, 8*k+0); s0 += a.x * bg; s1 += c.x * bg;
                bg = readlane_f(Bown, 8*k+2); s0 += a.y * bg; s1 += c.y * bg;
                bg = readlane_f(Bown, 8*k+4); s0 += a.z * bg; s1 += c.z * bg;
                bg = readlane_f(Bown, 8*k+6); s0 += a.w * bg; s1 += c.w * bg;
            }
        }
        Ac[0] *= clampf(Cc[0] / fmaxf(Ac[0] * s0, 1e-12f), 0.75f, 1.25f);
        Ac[1] *= clampf(Cc[1] / fmaxf(Ac[1] * s1, 1e-12f), 0.75f, 1.25f);

        // stop CSE from merging the two passes back into a 96-reg live set
        asm volatile("" ::: "memory");

        // ---- row pass: v[g] = y0[g,d0]*A[d0] + y0[g,d1]*A[d1] ----
        float v[NG];
        if (lcls) {
            #pragma unroll
            for (int k = 0; k < 8; ++k) {
                const int ro = 16 * ((k + rot) & 7);
                const float4 a = *(const float4*)(base0 + ro);
                const float4 c = *(const float4*)(base1 + ro);
                v[4*k+0] = a.x * Ac[0] + c.x * Ac[1];
                v[4*k+1] = a.y * Ac[0] + c.y * Ac[1];
                v[4*k+2] = a.z * Ac[0] + c.z * Ac[1];
                v[4*k+3] = a.w * Ac[0] + c.w * Ac[1];
            }
        } else if (valid) {
            #pragma unroll
            for (int k = 0; k < 8; ++k) {
                const float4 a = gp[k];
                const float4 c = gp[8 + k];
                v[4*k+0] = a.x * Ac[0] + c.x * Ac[1];
                v[4*k+1] = a.y * Ac[0] + c.y * Ac[1];
                v[4*k+2] = a.z * Ac[0] + c.z * Ac[1];
                v[4*k+3] = a.w * Ac[0] + c.w * Ac[1];
            }
        } else {
            #pragma unroll
            for (int g = 0; g < NG; ++g) v[g] = 0.f;
        }
        const float tot = wave_sum32(v, lane);
        const int buf = (q & 1) * (NWAVES * NG);
        if ((lane & 1) == 0) wred[buf + w * NG + g_own] = tot;
        __syncthreads();
        float s = 0.f;
        #pragma unroll
        for (int w2 = 0; w2 < NWAVES; ++w2) s += wred[buf + w2 * NG + g_own];
        Bown *= clampf(Rown / fmaxf(Bown * s, 1e-12f), 0.75f, 1.25f);
    }

    // epilogue: final scale + exact integerization (round-2 code, y0 reloaded)
    if (!valid) return;

    #pragma unroll
    for (int j = 0; j < 2; ++j) {
        float fr[NG];
        int   yv[NG];
        float s = 0.f;
        const char* basej = (j == 0) ? base0 : base1;
        if (lcls) {
            #pragma unroll
            for (int k = 0; k < 8; ++k) {
                const int ro = 16 * ((k + rot) & 7);
                const float4 a = *(const float4*)(basej + ro);
                float z;
                z = a.x * Ac[j] * readlane_f(Bown, 8*k+0); fr[4*k+0] = z; s += z;
                z = a.y * Ac[j] * readlane_f(Bown, 8*k+2); fr[4*k+1] = z; s += z;
                z = a.z * Ac[j] * readlane_f(Bown, 8*k+4); fr[4*k+2] = z; s += z;
                z = a.w * Ac[j] * readlane_f(Bown, 8*k+6); fr[4*k+3] = z; s += z;
            }
        } else {
            #pragma unroll
            for (int k = 0; k < 8; ++k) {
                const float4 a = gp[j * 8 + k];
                float z;
                z = a.x * Ac[j] * readlane_f(Bown, 8*k+0); fr[4*k+0] = z; s += z;
                z = a.y * Ac[j] * readlane_f(Bown, 8*k+2); fr[4*k+1] = z; s += z;
                z = a.z * Ac[j] * readlane_f(Bown, 8*k+4); fr[4*k+2] = z; s += z;
                z = a.w * Ac[j] * readlane_f(Bown, 8*k+6); fr[4*k+3] = z; s += z;
            }
        }
        const float F = Cc[j] / fmaxf(s, 1e-12f);
        int isum = 0;
        #pragma unroll
        for (int g = 0; g < NG; ++g) {
            const float y = fr[g] * F;
            const float fl = floorf(y);
            yv[g] = (int)fl;
            fr[g] = y - fl;
            isum += yv[g];
        }
        const int Ci = (int)Cc[j];
        const int need = Ci - isum;
        const int pos = max(need, 0);
        const int qq = pos >> 5;
        const int r = pos & 31;
        #pragma unroll
        for (int g = 0; g < NG; ++g) yv[g] += qq;
        #pragma unroll
        for (int g = 0; g < NG; ++g) {       // stable DESCENDING rank on frac
            int rank = 0;
            #pragma unroll
            for (int h = 0; h < NG; ++h) {
                if (h == g) continue;
                rank += (h < g) ? (fr[h] >= fr[g] ? 1 : 0) : (fr[h] > fr[g] ? 1 : 0);
            }
            if (rank < r) yv[g] += 1;
        }
        // negative residual: one-shot ascending rank among yv>0 (== reference)
        int neg = max(-need, 0);
        neg = min(neg, isum);
        if (__builtin_expect(neg > 0, 0)) {
            const int q2 = neg >> 5;
            int removed = 0;
            #pragma unroll
            for (int g = 0; g < NG; ++g) {
                const int yb = yv[g];
                const int yn = max(yb - q2, 0);
                removed += yb - yn;
                yv[g] = yn;
            }
            const int r2 = neg - removed;
            if (r2 > 0) {
                const float INF = __builtin_inff();
                #pragma unroll
                for (int g = 0; g < NG; ++g) {
                    const float fg = (yv[g] > 0) ? fr[g] : INF;
                    int rank = 0;
                    #pragma unroll
                    for (int h = 0; h < NG; ++h) {
                        if (h == g) continue;
                        const float fh = (yv[h] > 0) ? fr[h] : INF;
                        rank += (h < g) ? (fh <= fg ? 1 : 0) : (fh < fg ? 1 : 0);
                    }
                    if (rank < r2) yv[g] = max(yv[g] - 1, 0);
                }
            }
        }
        #pragma unroll
        for (int g = 0; g < NG; ++g)
            out[1 + (size_t)(b * NG + g) * ND + d0 + j] = (float)yv[g];
    }
}

// ---- loss-partials path: 256 blocks x 1024 thr = two 512-halves (verbatim
// from the passing round-2 kernel) --------------------------------------
__device__ __forceinline__ void loss_path(
        const float* __restrict__ x, const float* __restrict__ nl,
        const float* __restrict__ tgt, const float* __restrict__ W,
        const float* __restrict__ bias, float* __restrict__ res2,
        float* smem, int cx, int b, int tt) {
    const int half = cx & 1;
    float* xsl = smem;                         // 256 (shared across halves)
    float* nsl = smem + 256;                   // 256 (shared across halves)
    float* tgl = smem + 512 + half * 4284;     // 252 per half
    float* pt  = tgl + 252;                    // 16 x 252 per half

    if (half == 0 && tt < 256) {               // == global t < 256
        const float* xb = x + (size_t)b * NG * NDIN;
        float s = 0.f;
        for (int g = 0; g < NG; ++g) s += xb[g * NDIN + tt];
        xsl[tt] = s;
        const float* nb = nl + (size_t)b * NG * (NM * NE);
        float s2 = 0.f;
        for (int g = 0; g < NG; ++g) s2 += nb[g * (NM * NE) + tt];
        nsl[tt] = s2;
    }

    int tm = 0, tn = 0;
    if (tt >= 16 && tt < 152) {
        int p = tt - 16;
        for (int m = 0; m < NM; ++m) {
            int c = NM - m;
            if (p < c) { tm = m; tn = m + p; break; }
            p -= c;
        }
    }
    __syncthreads();

    const int d = cx * 250 + tt;
    if (tt < 250) {
        tgl[tt] = tgt[b * ND + d];
        float xw = 0.f;
        #pragma unroll 8
        for (int k = 0; k < NDIN; ++k) xw += xsl[k] * W[(size_t)k * ND + d];
        float we[NE];
        #pragma unroll
        for (int e = 0; e < NE; ++e) we[e] = W[(size_t)(NDIN + e) * ND + d];
        const float base0 = xw + (float)NG * bias[d];
        #pragma unroll
        for (int m = 0; m < NM; ++m) {
            float pm = base0;
            #pragma unroll
            for (int e = 0; e < NE; ++e) pm += nsl[m * NE + e] * we[e];
            pt[m * 252 + tt] = pm;
        }
    }
    if (tt < 32) {                     // zero-pad cols 250,251
        pt[(tt >> 1) * 252 + 250 + (tt & 1)] = 0.f;
        if (tt < 2) tgl[250 + tt] = 0.f;
    }
    __syncthreads();

    float acc = 0.f;
    if (tt < 16) {
        const float4* pa  = (const float4*)&pt[tt * 252];
        const float4* tga = (const float4*)&tgl[0];
        for (int i = 0; i < 63; ++i) {
            float4 pv = pa[i], tv = tga[i];
            float e0 = pv.x - tv.x, e1 = pv.y - tv.y, e2 = pv.z - tv.z, e3 = pv.w - tv.w;
            acc += e0 * e0 + e1 * e1 + e2 * e2 + e3 * e3;
        }
    } else if (tt < 152) {
        const float4* pa = (const float4*)&pt[tm * 252];
        const float4* pb = (const float4*)&pt[tn * 252];
        for (int i = 0; i < 63; ++i) {
            float4 u = pa[i], v = pb[i];
            acc += u.x * v.x + u.y * v.y + u.z * v.z + u.w * v.w;
        }
    }
    if (tt < 152) res2[((size_t)b * 8 + cx) * 152 + tt] = acc;
}

extern "C" __global__ __launch_bounds__(1024)
void mega(const float* __restrict__ x, const float* __restrict__ nl,
          const float* __restrict__ tgt, const float* __restrict__ W,
          const float* __restrict__ bias, const float* __restrict__ xpT,
          const int* __restrict__ tsum, float* __restrict__ out,
          float* __restrict__ res2) {
    extern __shared__ char smem[];     // 159744 B: 4 KB wred + 152 KB y0 cols
    const int bid = blockIdx.x;
    const int t = threadIdx.x;
    if (bid < NB) {
        ipf_path(xpT, tsum, out, smem, bid, t);
    } else {
        const int q = bid - NB;                    // 0..255
        const int b = q >> 2;                      // 0..63
        const int cx = ((q & 3) << 1) | (t >> 9);  // 0..7 (half = t>>9)
        loss_path(x, nl, tgt, W, bias, res2, (float*)smem, cx, b, t & 511);
    }
}

// K2b: combine the 8 d-chunk partials per b and accumulate the loss.
extern "C" __global__ __launch_bounds__(64)
void k2b_combine(const float* __restrict__ res2, float* __restrict__ out) {
    const int b = blockIdx.x, t = threadIdx.x;
    __shared__ float res[152];
    for (int tau = t; tau < 152; tau += 64) {
        float s = 0.f;
        #pragma unroll
        for (int c = 0; c < 8; ++c) s += res2[((size_t)b * 8 + c) * 152 + tau];
        res[tau] = s;
    }
    __syncthreads();
    if (t == 0) {
        float conf = 0.f;
        for (int m = 0; m < NM; ++m) conf += sqrtf(res[m]);
        conf *= (1.f / NM);
        float pd = 0.f;
        for (int m = 0; m < NM; ++m) {
            const int offm = 16 + m * NM - m * (m - 1) / 2;
            const float sqm = res[offm];
            for (int n = m + 1; n < NM; ++n) {
                const int offn = 16 + n * NM - n * (n - 1) / 2;
                const float sqn = res[offn];
                const float inn = res[offm + (n - m)];
                pd += sqrtf(fmaxf(sqm + sqn - 2.f * inn, 1e-6f));
            }
        }
        pd = 2.f * pd / (float)(NM * (NM - 1));
        atomicAdd(out, (conf - 0.5f * pd) * (1.f / NB));
    }
}

// ---------------------------------------------------------------------------
// K3: x_pred = softplus(concat(x, noise_sample) @ W + bias), stored
// TRANSPOSED as xpT[b][d][g] (g contiguous) so the IPF path reads columns
// as contiguous 128 B runs.  Compute structure unchanged from round 2.
// ---------------------------------------------------------------------------
extern "C" __global__ __launch_bounds__(256)
void k3_xpred(const float* __restrict__ x, const float* __restrict__ nsamp,
              const float* __restrict__ W, const float* __restrict__ bias,
              float* __restrict__ xpT) {
    const int dx = blockIdx.x;     // 0..1
    const int rb = blockIdx.y;     // 0..255
    const int t  = threadIdx.x;
    __shared__ float xr[8][NK];
    #pragma unroll
    for (int r = 0; r < 8; ++r) {
        const int row = rb * 8 + r;
        xr[r][t] = x[(size_t)row * NDIN + t];
        if (t < NE) xr[r][NDIN + t] = nsamp[row * NE + t];
    }
    __syncthreads();
    if (t >= 250) return;
    const int d = dx * 1000 + 4 * t;
    float acc[8][4];
    #pragma unroll
    for (int r = 0; r < 8; ++r) {
        acc[r][0] = 0.f; acc[r][1] = 0.f; acc[r][2] = 0.f; acc[r][3] = 0.f;
    }
    for (int k = 0; k < NK; k += 4) {
        float4 w[4];
        #pragma unroll
        for (int kk = 0; kk < 4; ++kk) w[kk] = *(const float4*)&W[(size_t)(k + kk) * ND + d];
        #pragma unroll
        for (int r = 0; r < 8; ++r) {
            const float4 xv = *(const float4*)&xr[r][k];
            acc[r][0] += xv.x * w[0].x + xv.y * w[1].x + xv.z * w[2].x + xv.w * w[3].x;
            acc[r][1] += xv.x * w[0].y + xv.y * w[1].y + xv.z * w[2].y + xv.w * w[3].y;
            acc[r][2] += xv.x * w[0].z + xv.y * w[1].z + xv.z * w[2].z + xv.w * w[3].z;
            acc[r][3] += xv.x * w[0].w + xv.y * w[1].w + xv.z * w[2].w + xv.w * w[3].w;
        }
    }
    const float4 bv = *(const float4*)&bias[d];
    const float bvv[4] = {bv.x, bv.y, bv.z, bv.w};
    const int b2 = rb >> 2;            // b = row/32
    const int g0 = (rb & 3) * 8;       // this thread-block's 8-g slice
    #pragma unroll
    for (int dd = 0; dd < 4; ++dd) {
        float* op = xpT + ((size_t)b2 * ND + (d + dd)) * NG + g0;
        float4 lo, hi;
        lo.x = softplusf(acc[0][dd] + bvv[dd]);
        lo.y = softplusf(acc[1][dd] + bvv[dd]);
        lo.z = softplusf(acc[2][dd] + bvv[dd]);
        lo.w = softplusf(acc[3][dd] + bvv[dd]);
        hi.x = softplusf(acc[4][dd] + bvv[dd]);
        hi.y = softplusf(acc[5][dd] + bvv[dd]);
        hi.z = softplusf(acc[6][dd] + bvv[dd]);
        hi.w = softplusf(acc[7][dd] + bvv[dd]);
        *(float4*)op       = lo;
        *(float4*)(op + 4) = hi;
    }
}

// ---------------------------------------------------------------------------
extern "C" void kernel_launch(void* const* d_in, const int* in_sizes, int n_in,
                              void* d_out, int out_size, void* d_ws, size_t ws_size,
                              hipStream_t stream) {
    const float* x     = (const float*)d_in[0];
    const float* tgt   = (const float*)d_in[1];
    const int*   tsum  = (const int*)d_in[2];
    const float* W     = (const float*)d_in[3];
    const float* bias  = (const float*)d_in[4];
    const float* nl    = (const float*)d_in[5];
    const float* nsamp = (const float*)d_in[6];
    float* out = (float*)d_out;
    float* xpT = (float*)d_ws;                         // 64*2000*32 floats

    (void)in_sizes; (void)n_in; (void)out_size; (void)ws_size;

    const size_t XPB = (size_t)2048 * 2000 * 4;        // 16,384,000 B
    float* res2 = (float*)((char*)d_ws + XPB);         // 64*8*152 floats

    static int s_attr_done = 0;
    if (!s_attr_done) {
        hipFuncSetAttribute(reinterpret_cast<const void*>(mega),
                            hipFuncAttributeMaxDynamicSharedMemorySize,
                            SMEM_BYTES);
        s_attr_done = 1;
    }

    hipMemsetAsync(d_out, 0, sizeof(float), stream);   // loss accumulator

    hipLaunchKernelGGL(k3_xpred, dim3(2, 256), dim3(256), 0, stream,
                       x, nsamp, W, bias, xpT);
    hipLaunchKernelGGL(mega, dim3(NB + 256), dim3(1024), SMEM_BYTES, stream,
                       x, nl, tgt, W, bias, xpT, tsum, out, res2);
    hipLaunchKernelGGL(k2b_combine, dim3(NB), dim3(64), 0, stream, res2, out);
}